// Round 11
// baseline (179.669 us; speedup 1.0000x reference)
//
#include <hip/hip_runtime.h>
#include <cstddef>
#include <cstdint>

typedef __attribute__((ext_vector_type(8))) short short8;
typedef __attribute__((ext_vector_type(4))) short s16x4;
typedef __attribute__((ext_vector_type(4))) float f32x4;
typedef __attribute__((ext_vector_type(16))) float f32x16;

#define GLOAD_LDS16(gp, lp) __builtin_amdgcn_global_load_lds( \
    (const __attribute__((address_space(1))) void*)(gp),      \
    (__attribute__((address_space(3))) void*)(lp), 16, 0, 0)

__device__ __forceinline__ short f2bf(float f) {
    union { float f; unsigned u; } v; v.f = f;
    unsigned r = v.u + 0x7fffu + ((v.u >> 16) & 1u);
    return (short)(r >> 16);
}

// ---------------------------------------------------------------------------
// Prep: the 5 weight transposes only (f32 [R][C] -> bf16 [C][R]). 352 blocks.
// ---------------------------------------------------------------------------
__global__ __launch_bounds__(256) void prep_kernel(
    const float* __restrict__ Wq, const float* __restrict__ Wk,
    const float* __restrict__ Wv, const float* __restrict__ W1,
    const float* __restrict__ W2,
    short* WqT, short* WkT, short* WvT, short* W1T, short* W2T)
{
    __shared__ short tile[64][68];
    int b2 = blockIdx.x;
    const float* in; short* out; int R, C;
    if (b2 < 16)       { in = Wq; out = WqT; R = 512;  C = 128; }
    else if (b2 < 32)  { in = Wk; out = WkT; R = 512;  C = 128;  b2 -= 16; }
    else if (b2 < 96)  { in = Wv; out = WvT; R = 512;  C = 512;  b2 -= 32; }
    else if (b2 < 224) { in = W1; out = W1T; R = 512;  C = 1024; b2 -= 96; }
    else               { in = W2; out = W2T; R = 1024; C = 512;  b2 -= 224; }
    int nx = C >> 6;
    int r0 = (b2 / nx) * 64, c0 = (b2 % nx) * 64;
    int t = threadIdx.x, tr = t >> 6, tc = t & 63;
#pragma unroll
    for (int i = 0; i < 16; ++i) {
        int r = i * 4 + tr;
        tile[r][tc] = f2bf(in[(size_t)(r0 + r) * C + (c0 + tc)]);
    }
    __syncthreads();
#pragma unroll
    for (int i = 0; i < 16; ++i) {
        int r = i * 4 + tr;
        out[(size_t)(c0 + r) * R + (r0 + tc)] = tile[tc][r];
    }
}

// ---------------------------------------------------------------------------
// Fused q/k/v projection GEMM reading f32 activations directly (cvt while
// staging A; store-side XOR swizzle). B via global_load_lds w=16.
// Outputs MFMA-fragment-major (frag-RC for q/k, frag-CR for v).
// ---------------------------------------------------------------------------
__global__ __launch_bounds__(256, 2) void proj_gemm(
    const float* __restrict__ x, const float* __restrict__ y,
    const short* __restrict__ WqT, const short* __restrict__ WkT,
    const short* __restrict__ WvT,
    short* __restrict__ qbf, short* __restrict__ kbff, short* __restrict__ vbf)
{
    __shared__ short As[128][64];
    __shared__ short Bs[128][64];
    int bid = blockIdx.x;
    const float* A; const short* BT; short* outp; int n0, N, mode, mb;
    if (bid < 128)      { A = x; BT = WqT; outp = qbf;  n0 = 0; N = 128; mode = 0; mb = bid; }
    else if (bid < 256) { A = y; BT = WkT; outp = kbff; n0 = 0; N = 128; mode = 0; mb = bid - 128; }
    else { int v2 = bid - 256; A = y; BT = WvT; outp = vbf; n0 = (v2 & 3) << 7; N = 512; mode = 1; mb = v2 >> 2; }
    const int m0 = mb << 7;
    const int K = 512;
    const int t = threadIdx.x, l = t & 63, w = t >> 6;
    const int wm = w >> 1, wn = w & 1;
    const int lo = l & 15, hi = l >> 4;

    f32x4 acc[4][4] = {};
    const int srow = l >> 3;
    const int scg  = (l & 7) ^ (srow & 7);

    for (int kt = 0; kt < K; kt += 64) {
#pragma unroll
        for (int i = 0; i < 4; ++i) {
            int seg = w * 4 + i;
            int row = seg * 8 + srow;
            GLOAD_LDS16(BT + (size_t)(n0 + row) * K + kt + scg * 8, &Bs[seg * 8][0]);
        }
#pragma unroll
        for (int i = 0; i < 4; ++i) {
            int c = i * 256 + t;
            int row = c >> 3, ch = c & 7;
            const float* src = A + (size_t)(m0 + row) * K + kt + ch * 8;
            f32x4 u0 = *(const f32x4*)src;
            f32x4 u1 = *(const f32x4*)(src + 4);
            int d0, d1, d2, d3;
            asm("v_cvt_pk_bf16_f32 %0, %1, %2" : "=v"(d0) : "v"(u0[0]), "v"(u0[1]));
            asm("v_cvt_pk_bf16_f32 %0, %1, %2" : "=v"(d1) : "v"(u0[2]), "v"(u0[3]));
            asm("v_cvt_pk_bf16_f32 %0, %1, %2" : "=v"(d2) : "v"(u1[0]), "v"(u1[1]));
            asm("v_cvt_pk_bf16_f32 %0, %1, %2" : "=v"(d3) : "v"(u1[2]), "v"(u1[3]));
            union { int i[4]; short8 v; } uu;
            uu.i[0] = d0; uu.i[1] = d1; uu.i[2] = d2; uu.i[3] = d3;
            *(short8*)&As[row][((ch ^ (row & 7)) * 8)] = uu.v;
        }
        __syncthreads();
#pragma unroll
        for (int kk = 0; kk < 2; ++kk) {
            short8 af[4], bfv[4];
            const int rc = ((kk * 4 + hi) ^ (lo & 7)) * 8;
#pragma unroll
            for (int mi = 0; mi < 4; ++mi)
                af[mi] = *(const short8*)&As[wm * 64 + mi * 16 + lo][rc];
#pragma unroll
            for (int ni = 0; ni < 4; ++ni)
                bfv[ni] = *(const short8*)&Bs[wn * 64 + ni * 16 + lo][rc];
            __builtin_amdgcn_s_setprio(1);
#pragma unroll
            for (int mi = 0; mi < 4; ++mi)
#pragma unroll
                for (int ni = 0; ni < 4; ++ni)
                    acc[mi][ni] = __builtin_amdgcn_mfma_f32_16x16x32_bf16(
                        af[mi], bfv[ni], acc[mi][ni], 0, 0, 0);
            __builtin_amdgcn_s_setprio(0);
        }
        __syncthreads();
    }

    if (mode == 0) {
#pragma unroll
        for (int mi = 0; mi < 4; ++mi) {
#pragma unroll
            for (int ni = 0; ni < 4; ++ni) {
                int rowb = m0 + wm * 64 + mi * 16 + hi * 4;
                int col  = n0 + wn * 64 + ni * 16 + lo;
                size_t base = ((size_t)(rowb >> 5) * (N >> 4) + (col >> 4)) * 512
                            + ((col & 15) >> 3) * 256 + (rowb & 31) * 8 + (col & 7);
#pragma unroll
                for (int r = 0; r < 4; ++r)
                    outp[base + r * 8] = f2bf(acc[mi][ni][r]);
            }
        }
    } else {
#pragma unroll
        for (int mi = 0; mi < 4; ++mi) {
#pragma unroll
            for (int ni = 0; ni < 4; ++ni) {
                int rowb = m0 + wm * 64 + mi * 16 + hi * 4;
                int col  = n0 + wn * 64 + ni * 16 + lo;
                size_t base = ((size_t)(rowb >> 4) * (N >> 5) + (col >> 5)) * 512
                            + ((rowb & 15) >> 3) * 256 + (col & 31) * 8 + (rowb & 7);
                s16x4 pk;
#pragma unroll
                for (int r = 0; r < 4; ++r) pk[r] = f2bf(acc[mi][ni][r]);
                *(s16x4*)(outp + base) = pk;
            }
        }
    }
}

// ---------------------------------------------------------------------------
// MLP GEMM with XCD-aware swizzle.
// EPI 2: +bias, exact GELU -> bf16. EPI 3: +bias +resid -> f32.
// ---------------------------------------------------------------------------
template<int EPI>
__global__ __launch_bounds__(256, 2) void gemm_kernel(
    const short* __restrict__ A, const short* __restrict__ BT, void* outv,
    const float* __restrict__ bias, const float* __restrict__ resid,
    int N, int K)
{
    __shared__ short As[128][64];
    __shared__ short Bs[128][64];
    int bid = blockIdx.x;
    const int cpx = gridDim.x >> 3;
    bid = (bid & 7) * cpx + (bid >> 3);     // XCD swizzle (grid % 8 == 0)
    const int nb = N >> 7;
    const int m0 = (bid / nb) << 7;
    const int n0 = (bid % nb) << 7;
    const int t = threadIdx.x, l = t & 63, w = t >> 6;
    const int wm = w >> 1, wn = w & 1;
    const int lo = l & 15, hi = l >> 4;

    f32x4 acc[4][4] = {};
    const int srow = l >> 3;
    const int scg  = (l & 7) ^ (srow & 7);

    for (int kt = 0; kt < K; kt += 64) {
#pragma unroll
        for (int i = 0; i < 4; ++i) {
            int seg = w * 4 + i;
            int row = seg * 8 + srow;
            GLOAD_LDS16(A + (size_t)(m0 + row) * K + kt + scg * 8, &As[seg * 8][0]);
        }
#pragma unroll
        for (int i = 0; i < 4; ++i) {
            int seg = w * 4 + i;
            int row = seg * 8 + srow;
            GLOAD_LDS16(BT + (size_t)(n0 + row) * K + kt + scg * 8, &Bs[seg * 8][0]);
        }
        __syncthreads();
#pragma unroll
        for (int kk = 0; kk < 2; ++kk) {
            short8 af[4], bfv[4];
            const int rc = ((kk * 4 + hi) ^ (lo & 7)) * 8;
#pragma unroll
            for (int mi = 0; mi < 4; ++mi)
                af[mi] = *(const short8*)&As[wm * 64 + mi * 16 + lo][rc];
#pragma unroll
            for (int ni = 0; ni < 4; ++ni)
                bfv[ni] = *(const short8*)&Bs[wn * 64 + ni * 16 + lo][rc];
            __builtin_amdgcn_s_setprio(1);
#pragma unroll
            for (int mi = 0; mi < 4; ++mi)
#pragma unroll
                for (int ni = 0; ni < 4; ++ni)
                    acc[mi][ni] = __builtin_amdgcn_mfma_f32_16x16x32_bf16(
                        af[mi], bfv[ni], acc[mi][ni], 0, 0, 0);
            __builtin_amdgcn_s_setprio(0);
        }
        __syncthreads();
    }

#pragma unroll
    for (int mi = 0; mi < 4; ++mi) {
#pragma unroll
        for (int ni = 0; ni < 4; ++ni) {
#pragma unroll
            for (int r = 0; r < 4; ++r) {
                int row = m0 + wm * 64 + mi * 16 + hi * 4 + r;
                int col = n0 + wn * 64 + ni * 16 + lo;
                size_t idx = (size_t)row * N + col;
                float v = acc[mi][ni][r];
                if (EPI == 2) {
                    v += bias[col];
                    v = 0.5f * v * (1.0f + erff(v * 0.70710678118654752f));
                    ((short*)outv)[idx] = f2bf(v);
                } else {
                    v += bias[col] + resid[idx];
                    ((float*)outv)[idx] = v;
                }
            }
        }
    }
}

// ---------------------------------------------------------------------------
// Flash attention + residual + FUSED LayerNorm. Fixed-m softmax (r10).
// NEW: 4-wave blocks, 32 q-rows, grid 512 -> 2 independent blocks/CU so the
// QK/softmax of one block overlaps the PV/mem of the other (breaks the
// 1-block lockstep that pinned all pipes at ~25%).
// Wave w: QK on key-quarter w (no dup); PV on vd-slice [w*128,(w+1)*128).
// P shared via Ps[2][8][512] (16KB, parity double-buffer, 1 barrier/tile).
// ---------------------------------------------------------------------------
__global__ __launch_bounds__(256, 2) void flash_kernel(
    const float* __restrict__ x,    // [8][2048][512] f32
    const short* __restrict__ qbf,  // frag-RC
    const short* __restrict__ kbff, // frag-RC
    const short* __restrict__ vbf,  // frag-CR
    float* __restrict__ xres,       // [8][2048][512] f32
    const float* __restrict__ gamma,
    const float* __restrict__ beta,
    short* __restrict__ hb)         // [16384][512] bf16 (LN output)
{
    __shared__ short Ps[2][8][512];      // [buf][key16-blk][lane*8] = 16 KB
    __shared__ float lpart[4][32];
    __shared__ float rsum[4][32];
    __shared__ float rsq[4][32];
    __shared__ float murs[2][32];

    const int bid = blockIdx.x;
    const int n = bid & 7;               // batch -> XCD affinity
    const int qtile = bid >> 3;          // 0..63
    const int q0 = qtile << 5;           // 32 q-rows per block
    const int t = threadIdx.x, l = t & 63, w = t >> 6;   // w = 0..3
    const int lo5 = l & 31, hi2 = l >> 5;
    const float C1 = 0.08838834764831845f * 1.4426950408889634f; // scale*log2e

    // Q B-fragments (shared rows, all waves identical)
    short8 qf[8];
    {
        const short* qp = qbf + (((size_t)(n * 64 + qtile) * 8) << 9) + l * 8;
#pragma unroll
        for (int s = 0; s < 8; ++s) qf[s] = *(const short8*)(qp + (s << 9));
    }

    f32x16 o[4] = {};                    // [vd32-blk][reg] : 32 q x 128 vd
    float lp = 0.f;

    const short* kb0 = kbff + (((size_t)(n * 64) * 8) << 9);
    const short* vb0 = vbf + (((size_t)(n * 128) * 16 + w * 4) << 9);

    short8 preg0, preg1;

    // ---- prologue: QK(0) on my key-quarter + exp2 + pack -> Ps[0] ----
    {
        const short* kp = kb0 + (((size_t)w * 8) << 9) + l * 8;
        short8 kf[8];
#pragma unroll
        for (int s = 0; s < 8; ++s) kf[s] = *(const short8*)(kp + (s << 9));
        f32x16 sa = {};
        __builtin_amdgcn_s_setprio(1);
#pragma unroll
        for (int s = 0; s < 8; ++s)
            sa = __builtin_amdgcn_mfma_f32_32x32x16_bf16(kf[s], qf[s], sa, 0, 0, 0);
        __builtin_amdgcn_s_setprio(0);
        float lsum = 0.f;
#pragma unroll
        for (int r = 0; r < 16; ++r) {
            float p = exp2f(sa[r] * C1);
            sa[r] = p; lsum += p;
        }
        lp = lsum;
        int wq[8], sx[8];
#pragma unroll
        for (int q2 = 0; q2 < 8; ++q2) {
            int a;
            asm("v_cvt_pk_bf16_f32 %0, %1, %2"
                : "=v"(a) : "v"(sa[2 * q2]), "v"(sa[2 * q2 + 1]));
            wq[q2] = a;
        }
#pragma unroll
        for (int q2 = 0; q2 < 8; ++q2) sx[q2] = __shfl_xor(wq[q2], 32);
        union { int i[4]; short8 v; } u0, u1;
        u0.i[0] = hi2 ? sx[2] : wq[0];
        u0.i[1] = hi2 ? sx[3] : wq[1];
        u0.i[2] = hi2 ? wq[2] : sx[0];
        u0.i[3] = hi2 ? wq[3] : sx[1];
        u1.i[0] = hi2 ? sx[6] : wq[4];
        u1.i[1] = hi2 ? sx[7] : wq[5];
        u1.i[2] = hi2 ? wq[6] : sx[4];
        u1.i[3] = hi2 ? wq[7] : sx[5];
        *(short8*)&Ps[0][w * 2][l * 8]     = u0.v;
        *(short8*)&Ps[0][w * 2 + 1][l * 8] = u1.v;
    }

    // ---- main loop: 16 tiles of 128 keys, 1 barrier/tile ----
    for (int kt2 = 0; kt2 < 16; ++kt2) {
        const bool hn = kt2 < 15;

        // QK(t+1) on my key-quarter + fixed-m softmax + pack (reg-local)
        if (hn) {
            const short* kp = kb0 + (((size_t)((kt2 + 1) * 4 + w) * 8) << 9) + l * 8;
            short8 kf[8];
#pragma unroll
            for (int s = 0; s < 8; ++s) kf[s] = *(const short8*)(kp + (s << 9));
            f32x16 sa = {};
            __builtin_amdgcn_s_setprio(1);
#pragma unroll
            for (int s = 0; s < 8; ++s)
                sa = __builtin_amdgcn_mfma_f32_32x32x16_bf16(kf[s], qf[s], sa, 0, 0, 0);
            __builtin_amdgcn_s_setprio(0);
            float lsum = 0.f;
#pragma unroll
            for (int r = 0; r < 16; ++r) {
                float p = exp2f(sa[r] * C1);
                sa[r] = p; lsum += p;
            }
            lp += lsum;
            int wq[8], sx[8];
#pragma unroll
            for (int q2 = 0; q2 < 8; ++q2) {
                int a;
                asm("v_cvt_pk_bf16_f32 %0, %1, %2"
                    : "=v"(a) : "v"(sa[2 * q2]), "v"(sa[2 * q2 + 1]));
                wq[q2] = a;
            }
#pragma unroll
            for (int q2 = 0; q2 < 8; ++q2) sx[q2] = __shfl_xor(wq[q2], 32);
            union { int i[4]; short8 v; } u0, u1;
            u0.i[0] = hi2 ? sx[2] : wq[0];
            u0.i[1] = hi2 ? sx[3] : wq[1];
            u0.i[2] = hi2 ? wq[2] : sx[0];
            u0.i[3] = hi2 ? wq[3] : sx[1];
            u1.i[0] = hi2 ? sx[6] : wq[4];
            u1.i[1] = hi2 ? sx[7] : wq[5];
            u1.i[2] = hi2 ? wq[6] : sx[4];
            u1.i[3] = hi2 ? wq[7] : sx[5];
            preg0 = u0.v; preg1 = u1.v;
        }

        __syncthreads();   // Ps[kt2&1] complete; safe to publish (kt2+1)&1

        if (hn) {
            const int nb2 = (kt2 + 1) & 1;
            *(short8*)&Ps[nb2][w * 2][l * 8]     = preg0;
            *(short8*)&Ps[nb2][w * 2 + 1][l * 8] = preg1;
        }

        // PV(t): my vd-slice (4 vd32-blocks), all 128 keys. V in 2 halves.
        const int pb = kt2 & 1;
        const short* vp = vb0 + (((size_t)(kt2 * 8) * 16) << 9) + l * 8;

        short8 vfa[16];
#pragma unroll
        for (int ks = 0; ks < 4; ++ks)
#pragma unroll
            for (int b = 0; b < 4; ++b)
                vfa[ks * 4 + b] = *(const short8*)(vp + (((size_t)(ks * 16 + b)) << 9));
        __builtin_amdgcn_s_setprio(1);
#pragma unroll
        for (int ks = 0; ks < 4; ++ks) {
            short8 p = *(const short8*)&Ps[pb][ks][l * 8];
#pragma unroll
            for (int b = 0; b < 4; ++b)
                o[b] = __builtin_amdgcn_mfma_f32_32x32x16_bf16(p, vfa[ks * 4 + b], o[b], 0, 0, 0);
        }
        __builtin_amdgcn_s_setprio(0);

        short8 vfb[16];
#pragma unroll
        for (int ks = 4; ks < 8; ++ks)
#pragma unroll
            for (int b = 0; b < 4; ++b)
                vfb[(ks - 4) * 4 + b] = *(const short8*)(vp + (((size_t)(ks * 16 + b)) << 9));
        __builtin_amdgcn_s_setprio(1);
#pragma unroll
        for (int ks = 4; ks < 8; ++ks) {
            short8 p = *(const short8*)&Ps[pb][ks][l * 8];
#pragma unroll
            for (int b = 0; b < 4; ++b)
                o[b] = __builtin_amdgcn_mfma_f32_32x32x16_bf16(p, vfb[(ks - 4) * 4 + b], o[b], 0, 0, 0);
        }
        __builtin_amdgcn_s_setprio(0);
    }

    // ---- epilogue: l-merge, normalize, residual -> xres; fused LN -> hb ----
    float l2 = lp + __shfl_xor(lp, 32);
    if (l < 32) lpart[w][l] = l2;
    __syncthreads();
    float li = 1.f / (lpart[0][lo5] + lpart[1][lo5] + lpart[2][lo5] + lpart[3][lo5]);
    const int c0 = w * 128 + lo5;
#pragma unroll
    for (int r = 0; r < 16; ++r) {
        int qr = (r & 3) + 8 * (r >> 2) + 4 * hi2;
        float ir = __shfl(li, qr);
        size_t base = ((size_t)(n * 2048 + q0 + qr) << 9) + c0;
        float v0 = x[base]      + o[0][r] * ir;
        float v1 = x[base + 32] + o[1][r] * ir;
        float v2 = x[base + 64] + o[2][r] * ir;
        float v3 = x[base + 96] + o[3][r] * ir;
        xres[base] = v0; xres[base + 32] = v1;
        xres[base + 64] = v2; xres[base + 96] = v3;
        o[0][r] = v0; o[1][r] = v1; o[2][r] = v2; o[3][r] = v3;
        float s = v0 + v1 + v2 + v3;
        float sq = v0 * v0 + v1 * v1 + v2 * v2 + v3 * v3;
#pragma unroll
        for (int mm = 1; mm < 32; mm <<= 1) {
            s += __shfl_xor(s, mm); sq += __shfl_xor(sq, mm);
        }
        if (lo5 == 0) { rsum[w][qr] = s; rsq[w][qr] = sq; }
    }
    __syncthreads();
    if (t < 32) {
        float s  = rsum[0][t] + rsum[1][t] + rsum[2][t] + rsum[3][t];
        float qq = rsq[0][t]  + rsq[1][t]  + rsq[2][t]  + rsq[3][t];
        float mu = s * (1.0f / 512.0f);
        float var = qq * (1.0f / 512.0f) - mu * mu;
        murs[0][t] = mu;
        murs[1][t] = rsqrtf(var + 1e-5f);
    }
    __syncthreads();
    const float g0 = gamma[c0], g1 = gamma[c0 + 32];
    const float g2 = gamma[c0 + 64], g3 = gamma[c0 + 96];
    const float e0 = beta[c0],  e1 = beta[c0 + 32];
    const float e2 = beta[c0 + 64], e3 = beta[c0 + 96];
#pragma unroll
    for (int r = 0; r < 16; ++r) {
        int qr = (r & 3) + 8 * (r >> 2) + 4 * hi2;
        float mu = murs[0][qr], rs = murs[1][qr];
        size_t base = ((size_t)(n * 2048 + q0 + qr) << 9) + c0;
        hb[base]      = f2bf((o[0][r] - mu) * rs * g0 + e0);
        hb[base + 32] = f2bf((o[1][r] - mu) * rs * g1 + e1);
        hb[base + 64] = f2bf((o[2][r] - mu) * rs * g2 + e2);
        hb[base + 96] = f2bf((o[3][r] - mu) * rs * g3 + e3);
    }
}

// ---------------------------------------------------------------------------
extern "C" void kernel_launch(void* const* d_in, const int* in_sizes, int n_in,
                              void* d_out, int out_size, void* d_ws, size_t ws_size,
                              hipStream_t stream)
{
    const float* x     = (const float*)d_in[0];
    const float* y     = (const float*)d_in[1];
    const float* Wq    = (const float*)d_in[2];
    const float* Wk    = (const float*)d_in[3];
    const float* Wv    = (const float*)d_in[4];
    const float* gamma = (const float*)d_in[5];
    const float* beta  = (const float*)d_in[6];
    const float* W1    = (const float*)d_in[7];
    const float* b1    = (const float*)d_in[8];
    const float* W2    = (const float*)d_in[9];
    const float* b2    = (const float*)d_in[10];
    float* out = (float*)d_out;

    char* ws = (char*)d_ws;
    size_t off = 0;
    auto alloc = [&](size_t bytes) -> void* {
        void* p = ws + off;
        off += (bytes + 255) & ~(size_t)255;
        return p;
    };
    short* WqT  = (short*)alloc((size_t)128 * 512 * 2);
    short* WkT  = (short*)alloc((size_t)128 * 512 * 2);
    short* WvT  = (short*)alloc((size_t)512 * 512 * 2);
    short* W1T  = (short*)alloc((size_t)1024 * 512 * 2);
    short* W2T  = (short*)alloc((size_t)512 * 1024 * 2);
    short* qbf  = (short*)alloc((size_t)16384 * 128 * 2);   // frag-RC
    short* kbff = (short*)alloc((size_t)16384 * 128 * 2);   // frag-RC
    short* vbf  = (short*)alloc((size_t)16384 * 512 * 2);   // frag-CR
    short* hb   = (short*)alloc((size_t)16384 * 512 * 2);
    short* gb   = (short*)alloc((size_t)16384 * 1024 * 2);

    // 1. prep: weight transposes only
    prep_kernel<<<352, 256, 0, stream>>>(Wq, Wk, Wv, W1, W2,
                                         WqT, WkT, WvT, W1T, W2T);
    // 2. fused q/k/v projections (read f32 x,y directly) -> frag-major
    proj_gemm<<<768, 256, 0, stream>>>(x, y, WqT, WkT, WvT, qbf, kbff, vbf);
    // 3. attention + residual + fused LN -> xres(d_out), hb
    flash_kernel<<<512, 256, 0, stream>>>(x, qbf, kbff, vbf, out, gamma, beta, hb);
    // 4. MLP
    gemm_kernel<2><<<1024, 256, 0, stream>>>(hb, W1T, gb, b1, nullptr, 1024, 512);
    gemm_kernel<3><<<512,  256, 0, stream>>>(gb, W2T, out, b2, out, 512, 1024);

    (void)in_sizes; (void)n_in; (void)out_size; (void)ws_size;
}

// Round 13
// 172.351 us; speedup vs baseline: 1.0425x; 1.0425x over previous
//
#include <hip/hip_runtime.h>
#include <cstddef>
#include <cstdint>

typedef __attribute__((ext_vector_type(8))) short short8;
typedef __attribute__((ext_vector_type(4))) short s16x4;
typedef __attribute__((ext_vector_type(4))) float f32x4;
typedef __attribute__((ext_vector_type(16))) float f32x16;

#define GLOAD_LDS16(gp, lp) __builtin_amdgcn_global_load_lds( \
    (const __attribute__((address_space(1))) void*)(gp),      \
    (__attribute__((address_space(3))) void*)(lp), 16, 0, 0)

__device__ __forceinline__ short f2bf(float f) {
    union { float f; unsigned u; } v; v.f = f;
    unsigned r = v.u + 0x7fffu + ((v.u >> 16) & 1u);
    return (short)(r >> 16);
}

// ---------------------------------------------------------------------------
// Prep: Wq/Wk/Wv transposes (f32 [K][N] -> bf16 [N][K]) + W1 -> frag-RC
// + W2 -> frag-CR. 608 blocks: 96 transpose + 256 (W1) + 256 (W2).
// ---------------------------------------------------------------------------
__global__ __launch_bounds__(256) void prep_kernel(
    const float* __restrict__ Wq, const float* __restrict__ Wk,
    const float* __restrict__ Wv, const float* __restrict__ W1,
    const float* __restrict__ W2,
    short* WqT, short* WkT, short* WvT, short* W1F, short* W2F)
{
    int bid = blockIdx.x, t = threadIdx.x;
    if (bid < 96) {
        __shared__ short tile[64][68];
        int b2 = bid;
        const float* in; short* out; int R, C;
        if (b2 < 16)      { in = Wq; out = WqT; R = 512; C = 128; }
        else if (b2 < 32) { in = Wk; out = WkT; R = 512; C = 128; b2 -= 16; }
        else              { in = Wv; out = WvT; R = 512; C = 512; b2 -= 32; }
        int nx = C >> 6;
        int r0 = (b2 / nx) * 64, c0 = (b2 % nx) * 64;
        int tr = t >> 6, tc = t & 63;
#pragma unroll
        for (int i = 0; i < 16; ++i) {
            int r = i * 4 + tr;
            tile[r][tc] = f2bf(in[(size_t)(r0 + r) * C + (c0 + tc)]);
        }
        __syncthreads();
#pragma unroll
        for (int i = 0; i < 16; ++i) {
            int r = i * 4 + tr;
            out[(size_t)(c0 + r) * R + (r0 + tc)] = tile[tc][r];
        }
    } else if (bid < 352) {
        // W1 [512][1024] f32 -> W1F frag-RC (256 blocks, full K=512 coverage)
        int flat = (bid - 96) * 256 + t;
        int nn = flat & 1023, kg = flat >> 10, k0 = kg * 8;
        short8 sv;
#pragma unroll
        for (int j = 0; j < 8; ++j)
            sv[j] = f2bf(W1[(size_t)(k0 + j) * 1024 + nn]);
        size_t base = ((size_t)(nn >> 5) * 32 + (k0 >> 4)) * 512
                    + ((k0 >> 3) & 1) * 256 + (nn & 31) * 8;
        *(short8*)(W1F + base) = sv;
    } else {
        // W2 [1024][512] f32 -> W2F frag-CR (256 blocks, full K=1024 coverage)
        int flat = (bid - 352) * 256 + t;
        int c = flat & 511, kg = flat >> 9, k0 = kg * 8;   // kg in [0,128)
        short8 sv;
#pragma unroll
        for (int j = 0; j < 8; ++j)
            sv[j] = f2bf(W2[(size_t)(k0 + j) * 512 + c]);
        size_t base = ((size_t)(k0 >> 4) * 16 + (c >> 5)) * 512
                    + ((k0 >> 3) & 1) * 256 + (c & 31) * 8;
        *(short8*)(W2F + base) = sv;
    }
}

// ---------------------------------------------------------------------------
// Fused q/k/v projection GEMM (unchanged from r10).
// ---------------------------------------------------------------------------
__global__ __launch_bounds__(256, 2) void proj_gemm(
    const float* __restrict__ x, const float* __restrict__ y,
    const short* __restrict__ WqT, const short* __restrict__ WkT,
    const short* __restrict__ WvT,
    short* __restrict__ qbf, short* __restrict__ kbff, short* __restrict__ vbf)
{
    __shared__ short As[128][64];
    __shared__ short Bs[128][64];
    int bid = blockIdx.x;
    const float* A; const short* BT; short* outp; int n0, N, mode, mb;
    if (bid < 128)      { A = x; BT = WqT; outp = qbf;  n0 = 0; N = 128; mode = 0; mb = bid; }
    else if (bid < 256) { A = y; BT = WkT; outp = kbff; n0 = 0; N = 128; mode = 0; mb = bid - 128; }
    else { int v2 = bid - 256; A = y; BT = WvT; outp = vbf; n0 = (v2 & 3) << 7; N = 512; mode = 1; mb = v2 >> 2; }
    const int m0 = mb << 7;
    const int K = 512;
    const int t = threadIdx.x, l = t & 63, w = t >> 6;
    const int wm = w >> 1, wn = w & 1;
    const int lo = l & 15, hi = l >> 4;

    f32x4 acc[4][4] = {};
    const int srow = l >> 3;
    const int scg  = (l & 7) ^ (srow & 7);

    for (int kt = 0; kt < K; kt += 64) {
#pragma unroll
        for (int i = 0; i < 4; ++i) {
            int seg = w * 4 + i;
            int row = seg * 8 + srow;
            GLOAD_LDS16(BT + (size_t)(n0 + row) * K + kt + scg * 8, &Bs[seg * 8][0]);
        }
#pragma unroll
        for (int i = 0; i < 4; ++i) {
            int c = i * 256 + t;
            int row = c >> 3, ch = c & 7;
            const float* src = A + (size_t)(m0 + row) * K + kt + ch * 8;
            f32x4 u0 = *(const f32x4*)src;
            f32x4 u1 = *(const f32x4*)(src + 4);
            int d0, d1, d2, d3;
            asm("v_cvt_pk_bf16_f32 %0, %1, %2" : "=v"(d0) : "v"(u0[0]), "v"(u0[1]));
            asm("v_cvt_pk_bf16_f32 %0, %1, %2" : "=v"(d1) : "v"(u0[2]), "v"(u0[3]));
            asm("v_cvt_pk_bf16_f32 %0, %1, %2" : "=v"(d2) : "v"(u1[0]), "v"(u1[1]));
            asm("v_cvt_pk_bf16_f32 %0, %1, %2" : "=v"(d3) : "v"(u1[2]), "v"(u1[3]));
            union { int i[4]; short8 v; } uu;
            uu.i[0] = d0; uu.i[1] = d1; uu.i[2] = d2; uu.i[3] = d3;
            *(short8*)&As[row][((ch ^ (row & 7)) * 8)] = uu.v;
        }
        __syncthreads();
#pragma unroll
        for (int kk = 0; kk < 2; ++kk) {
            short8 af[4], bfv[4];
            const int rc = ((kk * 4 + hi) ^ (lo & 7)) * 8;
#pragma unroll
            for (int mi = 0; mi < 4; ++mi)
                af[mi] = *(const short8*)&As[wm * 64 + mi * 16 + lo][rc];
#pragma unroll
            for (int ni = 0; ni < 4; ++ni)
                bfv[ni] = *(const short8*)&Bs[wn * 64 + ni * 16 + lo][rc];
            __builtin_amdgcn_s_setprio(1);
#pragma unroll
            for (int mi = 0; mi < 4; ++mi)
#pragma unroll
                for (int ni = 0; ni < 4; ++ni)
                    acc[mi][ni] = __builtin_amdgcn_mfma_f32_16x16x32_bf16(
                        af[mi], bfv[ni], acc[mi][ni], 0, 0, 0);
            __builtin_amdgcn_s_setprio(0);
        }
        __syncthreads();
    }

    if (mode == 0) {
#pragma unroll
        for (int mi = 0; mi < 4; ++mi) {
#pragma unroll
            for (int ni = 0; ni < 4; ++ni) {
                int rowb = m0 + wm * 64 + mi * 16 + hi * 4;
                int col  = n0 + wn * 64 + ni * 16 + lo;
                size_t base = ((size_t)(rowb >> 5) * (N >> 4) + (col >> 4)) * 512
                            + ((col & 15) >> 3) * 256 + (rowb & 31) * 8 + (col & 7);
#pragma unroll
                for (int r = 0; r < 4; ++r)
                    outp[base + r * 8] = f2bf(acc[mi][ni][r]);
            }
        }
    } else {
#pragma unroll
        for (int mi = 0; mi < 4; ++mi) {
#pragma unroll
            for (int ni = 0; ni < 4; ++ni) {
                int rowb = m0 + wm * 64 + mi * 16 + hi * 4;
                int col  = n0 + wn * 64 + ni * 16 + lo;
                size_t base = ((size_t)(rowb >> 4) * (N >> 5) + (col >> 5)) * 512
                            + ((rowb & 15) >> 3) * 256 + (col & 31) * 8 + (rowb & 7);
                s16x4 pk;
#pragma unroll
                for (int r = 0; r < 4; ++r) pk[r] = f2bf(acc[mi][ni][r]);
                *(s16x4*)(outp + base) = pk;
            }
        }
    }
}

// ---------------------------------------------------------------------------
// MEGA-FUSED: flash attention (r10 structure, fixed-m softmax) + residual
// + LayerNorm + full MLP (GELU) + final residual -> d_out. One kernel.
// ---------------------------------------------------------------------------
__global__ __launch_bounds__(512, 1) void fused_kernel(
    const float* __restrict__ x,    // [8][2048][512] f32
    const short* __restrict__ qbf,  // frag-RC
    const short* __restrict__ kbff, // frag-RC
    const short* __restrict__ vbf,  // frag-CR
    const float* __restrict__ gamma,
    const float* __restrict__ beta,
    const short* __restrict__ W1F,  // frag-RC [N=1024][K=512]
    const float* __restrict__ b1,
    const short* __restrict__ W2F,  // frag-CR [K=1024][N=512]
    const float* __restrict__ b2,
    float* __restrict__ out)        // [8][2048][512] f32
{
    __shared__ __align__(16) char smemA[65536];   // Ps (32KB) then h-tile (64KB)
    __shared__ __align__(16) char smemB[65536];   // gbf (64KB)
    __shared__ float lpart[8][32];
    __shared__ float rsum[8][64];
    __shared__ float rsq[8][64];
    __shared__ float murs[2][64];

    short* PsB = (short*)smemA;          // Ps[(buf*2+qh)*8+blk][512]
    short* hT  = (short*)smemA;          // h-tile after flash loop
    short* gbf = (short*)smemB;          // gbf[(hb2*32+kk)*512 + l*8]

    const int bid = blockIdx.x;
    const int n = bid & 7;
    const int qtile = bid >> 3;          // 0..31
    const int q0 = qtile << 6;
    const int t = threadIdx.x, l = t & 63, w = t >> 6;
    const int qh = w >> 2, kq = w & 3;
    const int lo5 = l & 31, hi2 = l >> 5;
    const float C1 = 0.08838834764831845f * 1.4426950408889634f; // scale*log2e

    // Q B-fragments for my q-half (32 q-rows)
    short8 qf[8];
    {
        const short* qp = qbf + (((size_t)(n * 64 + qtile * 2 + qh) * 8) << 9) + l * 8;
#pragma unroll
        for (int s = 0; s < 8; ++s) qf[s] = *(const short8*)(qp + (s << 9));
    }

    f32x16 o00 = {}, o01 = {}, o10 = {}, o11 = {};
    float lp = 0.f;

    const short* kb0 = kbff + (((size_t)(n * 64) * 8) << 9);
    const short* vb0 = vbf + ((((size_t)(n * 128)) * 16 + w * 2) << 9);

    short8 preg0, preg1;

    // ---- prologue: QK(0) + exp2 + pack -> Ps[0] ----
    {
        const short* kp = kb0 + (((size_t)kq * 8) << 9) + l * 8;
        short8 kf[8];
#pragma unroll
        for (int s = 0; s < 8; ++s) kf[s] = *(const short8*)(kp + (s << 9));
        f32x16 sa = {};
        __builtin_amdgcn_s_setprio(1);
#pragma unroll
        for (int s = 0; s < 8; ++s)
            sa = __builtin_amdgcn_mfma_f32_32x32x16_bf16(kf[s], qf[s], sa, 0, 0, 0);
        __builtin_amdgcn_s_setprio(0);
        float lsum = 0.f;
#pragma unroll
        for (int r = 0; r < 16; ++r) {
            float p = exp2f(sa[r] * C1);
            sa[r] = p; lsum += p;
        }
        lp = lsum;
        int wq[8], sx[8];
#pragma unroll
        for (int q2 = 0; q2 < 8; ++q2) {
            int a;
            asm("v_cvt_pk_bf16_f32 %0, %1, %2"
                : "=v"(a) : "v"(sa[2 * q2]), "v"(sa[2 * q2 + 1]));
            wq[q2] = a;
        }
#pragma unroll
        for (int q2 = 0; q2 < 8; ++q2) sx[q2] = __shfl_xor(wq[q2], 32);
        union { int i[4]; short8 v; } u0, u1;
        u0.i[0] = hi2 ? sx[2] : wq[0];
        u0.i[1] = hi2 ? sx[3] : wq[1];
        u0.i[2] = hi2 ? wq[2] : sx[0];
        u0.i[3] = hi2 ? wq[3] : sx[1];
        u1.i[0] = hi2 ? sx[6] : wq[4];
        u1.i[1] = hi2 ? sx[7] : wq[5];
        u1.i[2] = hi2 ? wq[6] : sx[4];
        u1.i[3] = hi2 ? wq[7] : sx[5];
        *(short8*)&PsB[((0 * 2 + qh) * 8 + kq * 2) * 512 + l * 8]     = u0.v;
        *(short8*)&PsB[((0 * 2 + qh) * 8 + kq * 2 + 1) * 512 + l * 8] = u1.v;
    }

    // ---- flash main loop: 16 tiles of 128 keys, 1 barrier/tile ----
    for (int kt2 = 0; kt2 < 16; ++kt2) {
        const bool hn = kt2 < 15;
        const short* vp = vb0 + (((size_t)(kt2 * 128)) << 9) + l * 8;

        short8 kf[8];
        if (hn) {
            const short* kp = kb0 + (((size_t)((kt2 + 1) * 4 + kq) * 8) << 9) + l * 8;
#pragma unroll
            for (int s = 0; s < 8; ++s) kf[s] = *(const short8*)(kp + (s << 9));
        }
        short8 vfa[8];
#pragma unroll
        for (int p = 0; p < 8; ++p)
            vfa[p] = *(const short8*)(vp + (((size_t)((p >> 1) * 16 + (p & 1))) << 9));

        if (hn) {
            f32x16 sa = {};
            __builtin_amdgcn_s_setprio(1);
#pragma unroll
            for (int s = 0; s < 8; ++s)
                sa = __builtin_amdgcn_mfma_f32_32x32x16_bf16(kf[s], qf[s], sa, 0, 0, 0);
            __builtin_amdgcn_s_setprio(0);
            float lsum = 0.f;
#pragma unroll
            for (int r = 0; r < 16; ++r) {
                float p = exp2f(sa[r] * C1);
                sa[r] = p; lsum += p;
            }
            lp += lsum;
            int wq[8], sx[8];
#pragma unroll
            for (int q2 = 0; q2 < 8; ++q2) {
                int a;
                asm("v_cvt_pk_bf16_f32 %0, %1, %2"
                    : "=v"(a) : "v"(sa[2 * q2]), "v"(sa[2 * q2 + 1]));
                wq[q2] = a;
            }
#pragma unroll
            for (int q2 = 0; q2 < 8; ++q2) sx[q2] = __shfl_xor(wq[q2], 32);
            union { int i[4]; short8 v; } u0, u1;
            u0.i[0] = hi2 ? sx[2] : wq[0];
            u0.i[1] = hi2 ? sx[3] : wq[1];
            u0.i[2] = hi2 ? wq[2] : sx[0];
            u0.i[3] = hi2 ? wq[3] : sx[1];
            u1.i[0] = hi2 ? sx[6] : wq[4];
            u1.i[1] = hi2 ? sx[7] : wq[5];
            u1.i[2] = hi2 ? wq[6] : sx[4];
            u1.i[3] = hi2 ? wq[7] : sx[5];
            preg0 = u0.v; preg1 = u1.v;
        }

        __syncthreads();

        short8 vfb[8];
#pragma unroll
        for (int p = 0; p < 8; ++p)
            vfb[p] = *(const short8*)(vp + (((size_t)((4 + (p >> 1)) * 16 + (p & 1))) << 9));

        if (hn) {
            const int nb2 = (kt2 + 1) & 1;
            *(short8*)&PsB[((nb2 * 2 + qh) * 8 + kq * 2) * 512 + l * 8]     = preg0;
            *(short8*)&PsB[((nb2 * 2 + qh) * 8 + kq * 2 + 1) * 512 + l * 8] = preg1;
        }

        const int pb = kt2 & 1;
        __builtin_amdgcn_s_setprio(1);
#pragma unroll
        for (int ks = 0; ks < 4; ++ks) {
            short8 p0 = *(const short8*)&PsB[((pb * 2 + 0) * 8 + ks) * 512 + l * 8];
            short8 p1 = *(const short8*)&PsB[((pb * 2 + 1) * 8 + ks) * 512 + l * 8];
            o00 = __builtin_amdgcn_mfma_f32_32x32x16_bf16(p0, vfa[ks * 2 + 0], o00, 0, 0, 0);
            o01 = __builtin_amdgcn_mfma_f32_32x32x16_bf16(p0, vfa[ks * 2 + 1], o01, 0, 0, 0);
            o10 = __builtin_amdgcn_mfma_f32_32x32x16_bf16(p1, vfa[ks * 2 + 0], o10, 0, 0, 0);
            o11 = __builtin_amdgcn_mfma_f32_32x32x16_bf16(p1, vfa[ks * 2 + 1], o11, 0, 0, 0);
        }
#pragma unroll
        for (int ks = 4; ks < 8; ++ks) {
            short8 p0 = *(const short8*)&PsB[((pb * 2 + 0) * 8 + ks) * 512 + l * 8];
            short8 p1 = *(const short8*)&PsB[((pb * 2 + 1) * 8 + ks) * 512 + l * 8];
            o00 = __builtin_amdgcn_mfma_f32_32x32x16_bf16(p0, vfb[(ks - 4) * 2 + 0], o00, 0, 0, 0);
            o01 = __builtin_amdgcn_mfma_f32_32x32x16_bf16(p0, vfb[(ks - 4) * 2 + 1], o01, 0, 0, 0);
            o10 = __builtin_amdgcn_mfma_f32_32x32x16_bf16(p1, vfb[(ks - 4) * 2 + 0], o10, 0, 0, 0);
            o11 = __builtin_amdgcn_mfma_f32_32x32x16_bf16(p1, vfb[(ks - 4) * 2 + 1], o11, 0, 0, 0);
        }
        __builtin_amdgcn_s_setprio(0);
    }

    // ---- attn epilogue: l-merge; v = x + o/l (KEPT IN REGISTERS) ----
    float l2 = lp + __shfl_xor(lp, 32);
    if (l < 32) lpart[w][l] = l2;
    __syncthreads();
    float li0 = 1.f / (lpart[0][lo5] + lpart[1][lo5] + lpart[2][lo5] + lpart[3][lo5]);
    float li1 = 1.f / (lpart[4][lo5] + lpart[5][lo5] + lpart[6][lo5] + lpart[7][lo5]);
    const int c0 = w * 64 + lo5;
#pragma unroll
    for (int r = 0; r < 16; ++r) {
        int qr = (r & 3) + 8 * (r >> 2) + 4 * hi2;
        float ir0 = __shfl(li0, qr);
        float ir1 = __shfl(li1, qr);
        size_t b0 = ((size_t)(n * 2048 + q0 + qr) << 9) + c0;
        size_t b1i = ((size_t)(n * 2048 + q0 + 32 + qr) << 9) + c0;
        float v00 = x[b0]       + o00[r] * ir0;
        float v01 = x[b0 + 32]  + o01[r] * ir0;
        float v10 = x[b1i]      + o10[r] * ir1;
        float v11 = x[b1i + 32] + o11[r] * ir1;
        o00[r] = v00; o01[r] = v01; o10[r] = v10; o11[r] = v11;
        float s = v00 + v01, sq = v00 * v00 + v01 * v01;
        float s1r = v10 + v11, sq1r = v10 * v10 + v11 * v11;
#pragma unroll
        for (int mm = 1; mm < 32; mm <<= 1) {
            s += __shfl_xor(s, mm); sq += __shfl_xor(sq, mm);
            s1r += __shfl_xor(s1r, mm); sq1r += __shfl_xor(sq1r, mm);
        }
        if (lo5 == 0) {
            rsum[w][qr] = s;        rsq[w][qr] = sq;
            rsum[w][32 + qr] = s1r; rsq[w][32 + qr] = sq1r;
        }
    }
    __syncthreads();
    if (t < 64) {
        float s = 0.f, qq = 0.f;
#pragma unroll
        for (int ww = 0; ww < 8; ++ww) { s += rsum[ww][t]; qq += rsq[ww][t]; }
        float mu = s * (1.0f / 512.0f);
        float var = qq * (1.0f / 512.0f) - mu * mu;
        murs[0][t] = mu;
        murs[1][t] = rsqrtf(var + 1e-5f);
    }
    __syncthreads();

    // ---- LN -> h-tile in LDS (bf16, chunk-XOR swizzled) ----
    {
        const float g0 = gamma[c0], g1 = gamma[c0 + 32];
        const float e0 = beta[c0],  e1 = beta[c0 + 32];
        const int d0 = c0, d1 = c0 + 32;
#pragma unroll
        for (int r = 0; r < 16; ++r) {
            int qr = (r & 3) + 8 * (r >> 2) + 4 * hi2;
            float mu0 = murs[0][qr],      rs0 = murs[1][qr];
            float mu1 = murs[0][32 + qr], rs1 = murs[1][32 + qr];
            int row0 = qr, row1 = 32 + qr;
            hT[row0 * 512 + (((d0 >> 3) ^ (row0 & 31)) << 3) + (d0 & 7)] =
                f2bf((o00[r] - mu0) * rs0 * g0 + e0);
            hT[row0 * 512 + (((d1 >> 3) ^ (row0 & 31)) << 3) + (d1 & 7)] =
                f2bf((o01[r] - mu0) * rs0 * g1 + e1);
            hT[row1 * 512 + (((d0 >> 3) ^ (row1 & 31)) << 3) + (d0 & 7)] =
                f2bf((o10[r] - mu1) * rs1 * g0 + e0);
            hT[row1 * 512 + (((d1 >> 3) ^ (row1 & 31)) << 3) + (d1 & 7)] =
                f2bf((o11[r] - mu1) * rs1 * g1 + e1);
        }
    }
    __syncthreads();   // h-tile complete

    // ---- fused MLP: 2 K-halves of the hidden dim ----
    f32x16 a2[2][2] = {};   // acc2[hrow-block][c-block], matches o layout
#pragma unroll 1
    for (int half = 0; half < 2; ++half) {
#pragma unroll
        for (int hb2 = 0; hb2 < 2; ++hb2) {
            // mlp1 swapped: S1[g][hrow] = sum_d W1[d][g] h[hrow][d]
            f32x16 s1[2] = {};
#pragma unroll 4
            for (int s = 0; s < 32; ++s) {
                int row = hb2 * 32 + lo5;
                int ch = (s * 2 + hi2) ^ (row & 31);
                short8 hf = *(const short8*)&hT[row * 512 + ch * 8];
#pragma unroll
                for (int gb = 0; gb < 2; ++gb) {
                    int nb = half * 16 + w * 2 + gb;
                    short8 w1v = *(const short8*)(W1F + (size_t)nb * 16384 + s * 512 + l * 8);
                    s1[gb] = __builtin_amdgcn_mfma_f32_32x32x16_bf16(w1v, hf, s1[gb], 0, 0, 0);
                }
            }
            // bias + exact GELU (in-lane: lane = hrow, regs = g)
#pragma unroll
            for (int gb = 0; gb < 2; ++gb) {
#pragma unroll
                for (int r = 0; r < 16; ++r) {
                    int g = half * 512 + w * 64 + gb * 32 + (r & 3) + 8 * (r >> 2) + 4 * hi2;
                    float vv = s1[gb][r] + b1[g];
                    s1[gb][r] = 0.5f * vv * (1.0f + erff(vv * 0.70710678118654752f));
                }
            }
            // pack (flash P pipeline) -> gbf frags
#pragma unroll
            for (int gb = 0; gb < 2; ++gb) {
                int wq[8], sx[8];
#pragma unroll
                for (int q2 = 0; q2 < 8; ++q2) {
                    int a;
                    asm("v_cvt_pk_bf16_f32 %0, %1, %2"
                        : "=v"(a) : "v"(s1[gb][2 * q2]), "v"(s1[gb][2 * q2 + 1]));
                    wq[q2] = a;
                }
#pragma unroll
                for (int q2 = 0; q2 < 8; ++q2) sx[q2] = __shfl_xor(wq[q2], 32);
                union { int i[4]; short8 v; } u0, u1;
                u0.i[0] = hi2 ? sx[2] : wq[0];
                u0.i[1] = hi2 ? sx[3] : wq[1];
                u0.i[2] = hi2 ? wq[2] : sx[0];
                u0.i[3] = hi2 ? wq[3] : sx[1];
                u1.i[0] = hi2 ? sx[6] : wq[4];
                u1.i[1] = hi2 ? sx[7] : wq[5];
                u1.i[2] = hi2 ? wq[6] : sx[4];
                u1.i[3] = hi2 ? wq[7] : sx[5];
                int kk0 = w * 4 + gb * 2;
                *(short8*)&gbf[(hb2 * 32 + kk0) * 512 + l * 8]       = u0.v;
                *(short8*)&gbf[(hb2 * 32 + kk0 + 1) * 512 + l * 8]   = u1.v;
            }
        }
        __syncthreads();   // gbf(half) complete

        // mlp2: acc2 += gbf(half) @ W2F(half)
        __builtin_amdgcn_s_setprio(1);
#pragma unroll
        for (int hb2 = 0; hb2 < 2; ++hb2) {
#pragma unroll 4
            for (int kk = 0; kk < 32; ++kk) {
                short8 p = *(const short8*)&gbf[(hb2 * 32 + kk) * 512 + l * 8];
                int kkg = half * 32 + kk;
#pragma unroll
                for (int cb = 0; cb < 2; ++cb) {
                    short8 w2v = *(const short8*)(W2F + (size_t)(kkg * 16 + w * 2 + cb) * 512 + l * 8);
                    a2[hb2][cb] = __builtin_amdgcn_mfma_f32_32x32x16_bf16(p, w2v, a2[hb2][cb], 0, 0, 0);
                }
            }
        }
        __builtin_amdgcn_s_setprio(0);
        __syncthreads();   // before overwriting gbf with next half
    }

    // ---- final: out = v + mlp_out + b2 (coalesced, single write) ----
    const float bb0 = b2[c0], bb1 = b2[c0 + 32];
#pragma unroll
    for (int r = 0; r < 16; ++r) {
        int qr = (r & 3) + 8 * (r >> 2) + 4 * hi2;
        size_t b0 = ((size_t)(n * 2048 + q0 + qr) << 9) + c0;
        size_t b1i = ((size_t)(n * 2048 + q0 + 32 + qr) << 9) + c0;
        out[b0]       = o00[r] + a2[0][0][r] + bb0;
        out[b0 + 32]  = o01[r] + a2[0][1][r] + bb1;
        out[b1i]      = o10[r] + a2[1][0][r] + bb0;
        out[b1i + 32] = o11[r] + a2[1][1][r] + bb1;
    }
}

// ---------------------------------------------------------------------------
extern "C" void kernel_launch(void* const* d_in, const int* in_sizes, int n_in,
                              void* d_out, int out_size, void* d_ws, size_t ws_size,
                              hipStream_t stream)
{
    const float* x     = (const float*)d_in[0];
    const float* y     = (const float*)d_in[1];
    const float* Wq    = (const float*)d_in[2];
    const float* Wk    = (const float*)d_in[3];
    const float* Wv    = (const float*)d_in[4];
    const float* gamma = (const float*)d_in[5];
    const float* beta  = (const float*)d_in[6];
    const float* W1    = (const float*)d_in[7];
    const float* b1    = (const float*)d_in[8];
    const float* W2    = (const float*)d_in[9];
    const float* b2    = (const float*)d_in[10];
    float* out = (float*)d_out;

    char* ws = (char*)d_ws;
    size_t off = 0;
    auto alloc = [&](size_t bytes) -> void* {
        void* p = ws + off;
        off += (bytes + 255) & ~(size_t)255;
        return p;
    };
    short* WqT  = (short*)alloc((size_t)128 * 512 * 2);
    short* WkT  = (short*)alloc((size_t)128 * 512 * 2);
    short* WvT  = (short*)alloc((size_t)512 * 512 * 2);
    short* W1F  = (short*)alloc((size_t)1024 * 512 * 2);
    short* W2F  = (short*)alloc((size_t)1024 * 512 * 2);
    short* qbf  = (short*)alloc((size_t)16384 * 128 * 2);   // frag-RC
    short* kbff = (short*)alloc((size_t)16384 * 128 * 2);   // frag-RC
    short* vbf  = (short*)alloc((size_t)16384 * 512 * 2);   // frag-CR

    // 1. prep: Wq/Wk/Wv transposes + W1F/W2F fragment layouts (608 blocks!)
    prep_kernel<<<608, 256, 0, stream>>>(Wq, Wk, Wv, W1, W2,
                                         WqT, WkT, WvT, W1F, W2F);
    // 2. fused q/k/v projections (read f32 x,y directly) -> frag-major
    proj_gemm<<<768, 256, 0, stream>>>(x, y, WqT, WkT, WvT, qbf, kbff, vbf);
    // 3. attention + residual + LN + MLP + residual -> d_out
    fused_kernel<<<256, 512, 0, stream>>>(x, qbf, kbff, vbf, gamma, beta,
                                          W1F, b1, W2F, b2, out);

    (void)in_sizes; (void)n_in; (void)out_size; (void)ws_size;
}

// Round 14
// 169.047 us; speedup vs baseline: 1.0628x; 1.0195x over previous
//
#include <hip/hip_runtime.h>
#include <cstddef>
#include <cstdint>

typedef __attribute__((ext_vector_type(8))) short short8;
typedef __attribute__((ext_vector_type(4))) short s16x4;
typedef __attribute__((ext_vector_type(4))) float f32x4;
typedef __attribute__((ext_vector_type(16))) float f32x16;

#define GLOAD_LDS16(gp, lp) __builtin_amdgcn_global_load_lds( \
    (const __attribute__((address_space(1))) void*)(gp),      \
    (__attribute__((address_space(3))) void*)(lp), 16, 0, 0)

__device__ __forceinline__ short f2bf(float f) {
    union { float f; unsigned u; } v; v.f = f;
    unsigned r = v.u + 0x7fffu + ((v.u >> 16) & 1u);
    return (short)(r >> 16);
}

// ---------------------------------------------------------------------------
// Prep: the 5 weight transposes only (f32 [R][C] -> bf16 [C][R]). 352 blocks.
// ---------------------------------------------------------------------------
__global__ __launch_bounds__(256) void prep_kernel(
    const float* __restrict__ Wq, const float* __restrict__ Wk,
    const float* __restrict__ Wv, const float* __restrict__ W1,
    const float* __restrict__ W2,
    short* WqT, short* WkT, short* WvT, short* W1T, short* W2T)
{
    __shared__ short tile[64][68];
    int b2 = blockIdx.x;
    const float* in; short* out; int R, C;
    if (b2 < 16)       { in = Wq; out = WqT; R = 512;  C = 128; }
    else if (b2 < 32)  { in = Wk; out = WkT; R = 512;  C = 128;  b2 -= 16; }
    else if (b2 < 96)  { in = Wv; out = WvT; R = 512;  C = 512;  b2 -= 32; }
    else if (b2 < 224) { in = W1; out = W1T; R = 512;  C = 1024; b2 -= 96; }
    else               { in = W2; out = W2T; R = 1024; C = 512;  b2 -= 224; }
    int nx = C >> 6;
    int r0 = (b2 / nx) * 64, c0 = (b2 % nx) * 64;
    int t = threadIdx.x, tr = t >> 6, tc = t & 63;
#pragma unroll
    for (int i = 0; i < 16; ++i) {
        int r = i * 4 + tr;
        tile[r][tc] = f2bf(in[(size_t)(r0 + r) * C + (c0 + tc)]);
    }
    __syncthreads();
#pragma unroll
    for (int i = 0; i < 16; ++i) {
        int r = i * 4 + tr;
        out[(size_t)(c0 + r) * R + (r0 + tc)] = tile[tc][r];
    }
}

// ---------------------------------------------------------------------------
// Fused q/k/v projection GEMM reading f32 activations directly (cvt while
// staging A; store-side XOR swizzle). B via global_load_lds w=16.
// Outputs MFMA-fragment-major (frag-RC for q/k, frag-CR for v).
// launch_bounds(256,3): 3 blocks/CU so barrier drains overlap across blocks.
// ---------------------------------------------------------------------------
__global__ __launch_bounds__(256, 3) void proj_gemm(
    const float* __restrict__ x, const float* __restrict__ y,
    const short* __restrict__ WqT, const short* __restrict__ WkT,
    const short* __restrict__ WvT,
    short* __restrict__ qbf, short* __restrict__ kbff, short* __restrict__ vbf)
{
    __shared__ short As[128][64];
    __shared__ short Bs[128][64];
    int bid = blockIdx.x;
    const float* A; const short* BT; short* outp; int n0, N, mode, mb;
    if (bid < 128)      { A = x; BT = WqT; outp = qbf;  n0 = 0; N = 128; mode = 0; mb = bid; }
    else if (bid < 256) { A = y; BT = WkT; outp = kbff; n0 = 0; N = 128; mode = 0; mb = bid - 128; }
    else { int v2 = bid - 256; A = y; BT = WvT; outp = vbf; n0 = (v2 & 3) << 7; N = 512; mode = 1; mb = v2 >> 2; }
    const int m0 = mb << 7;
    const int K = 512;
    const int t = threadIdx.x, l = t & 63, w = t >> 6;
    const int wm = w >> 1, wn = w & 1;
    const int lo = l & 15, hi = l >> 4;

    f32x4 acc[4][4] = {};
    const int srow = l >> 3;
    const int scg  = (l & 7) ^ (srow & 7);

    for (int kt = 0; kt < K; kt += 64) {
#pragma unroll
        for (int i = 0; i < 4; ++i) {
            int seg = w * 4 + i;
            int row = seg * 8 + srow;
            GLOAD_LDS16(BT + (size_t)(n0 + row) * K + kt + scg * 8, &Bs[seg * 8][0]);
        }
#pragma unroll
        for (int i = 0; i < 4; ++i) {
            int c = i * 256 + t;
            int row = c >> 3, ch = c & 7;
            const float* src = A + (size_t)(m0 + row) * K + kt + ch * 8;
            f32x4 u0 = *(const f32x4*)src;
            f32x4 u1 = *(const f32x4*)(src + 4);
            int d0, d1, d2, d3;
            asm("v_cvt_pk_bf16_f32 %0, %1, %2" : "=v"(d0) : "v"(u0[0]), "v"(u0[1]));
            asm("v_cvt_pk_bf16_f32 %0, %1, %2" : "=v"(d1) : "v"(u0[2]), "v"(u0[3]));
            asm("v_cvt_pk_bf16_f32 %0, %1, %2" : "=v"(d2) : "v"(u1[0]), "v"(u1[1]));
            asm("v_cvt_pk_bf16_f32 %0, %1, %2" : "=v"(d3) : "v"(u1[2]), "v"(u1[3]));
            union { int i[4]; short8 v; } uu;
            uu.i[0] = d0; uu.i[1] = d1; uu.i[2] = d2; uu.i[3] = d3;
            *(short8*)&As[row][((ch ^ (row & 7)) * 8)] = uu.v;
        }
        __syncthreads();
#pragma unroll
        for (int kk = 0; kk < 2; ++kk) {
            short8 af[4], bfv[4];
            const int rc = ((kk * 4 + hi) ^ (lo & 7)) * 8;
#pragma unroll
            for (int mi = 0; mi < 4; ++mi)
                af[mi] = *(const short8*)&As[wm * 64 + mi * 16 + lo][rc];
#pragma unroll
            for (int ni = 0; ni < 4; ++ni)
                bfv[ni] = *(const short8*)&Bs[wn * 64 + ni * 16 + lo][rc];
            __builtin_amdgcn_s_setprio(1);
#pragma unroll
            for (int mi = 0; mi < 4; ++mi)
#pragma unroll
                for (int ni = 0; ni < 4; ++ni)
                    acc[mi][ni] = __builtin_amdgcn_mfma_f32_16x16x32_bf16(
                        af[mi], bfv[ni], acc[mi][ni], 0, 0, 0);
            __builtin_amdgcn_s_setprio(0);
        }
        __syncthreads();
    }

    if (mode == 0) {
#pragma unroll
        for (int mi = 0; mi < 4; ++mi) {
#pragma unroll
            for (int ni = 0; ni < 4; ++ni) {
                int rowb = m0 + wm * 64 + mi * 16 + hi * 4;
                int col  = n0 + wn * 64 + ni * 16 + lo;
                size_t base = ((size_t)(rowb >> 5) * (N >> 4) + (col >> 4)) * 512
                            + ((col & 15) >> 3) * 256 + (rowb & 31) * 8 + (col & 7);
#pragma unroll
                for (int r = 0; r < 4; ++r)
                    outp[base + r * 8] = f2bf(acc[mi][ni][r]);
            }
        }
    } else {
#pragma unroll
        for (int mi = 0; mi < 4; ++mi) {
#pragma unroll
            for (int ni = 0; ni < 4; ++ni) {
                int rowb = m0 + wm * 64 + mi * 16 + hi * 4;
                int col  = n0 + wn * 64 + ni * 16 + lo;
                size_t base = ((size_t)(rowb >> 4) * (N >> 5) + (col >> 5)) * 512
                            + ((rowb & 15) >> 3) * 256 + (col & 31) * 8 + (rowb & 7);
                s16x4 pk;
#pragma unroll
                for (int r = 0; r < 4; ++r) pk[r] = f2bf(acc[mi][ni][r]);
                *(s16x4*)(outp + base) = pk;
            }
        }
    }
}

// ---------------------------------------------------------------------------
// MLP GEMM with XCD-aware swizzle, 3 blocks/CU.
// EPI 2: +bias, exact GELU -> bf16. EPI 3: +bias +resid -> f32.
// ---------------------------------------------------------------------------
template<int EPI>
__global__ __launch_bounds__(256, 3) void gemm_kernel(
    const short* __restrict__ A, const short* __restrict__ BT, void* outv,
    const float* __restrict__ bias, const float* __restrict__ resid,
    int N, int K)
{
    __shared__ short As[128][64];
    __shared__ short Bs[128][64];
    int bid = blockIdx.x;
    const int cpx = gridDim.x >> 3;
    bid = (bid & 7) * cpx + (bid >> 3);     // XCD swizzle (grid % 8 == 0)
    const int nb = N >> 7;
    const int m0 = (bid / nb) << 7;
    const int n0 = (bid % nb) << 7;
    const int t = threadIdx.x, l = t & 63, w = t >> 6;
    const int wm = w >> 1, wn = w & 1;
    const int lo = l & 15, hi = l >> 4;

    f32x4 acc[4][4] = {};
    const int srow = l >> 3;
    const int scg  = (l & 7) ^ (srow & 7);

    for (int kt = 0; kt < K; kt += 64) {
#pragma unroll
        for (int i = 0; i < 4; ++i) {
            int seg = w * 4 + i;
            int row = seg * 8 + srow;
            GLOAD_LDS16(A + (size_t)(m0 + row) * K + kt + scg * 8, &As[seg * 8][0]);
        }
#pragma unroll
        for (int i = 0; i < 4; ++i) {
            int seg = w * 4 + i;
            int row = seg * 8 + srow;
            GLOAD_LDS16(BT + (size_t)(n0 + row) * K + kt + scg * 8, &Bs[seg * 8][0]);
        }
        __syncthreads();
#pragma unroll
        for (int kk = 0; kk < 2; ++kk) {
            short8 af[4], bfv[4];
            const int rc = ((kk * 4 + hi) ^ (lo & 7)) * 8;
#pragma unroll
            for (int mi = 0; mi < 4; ++mi)
                af[mi] = *(const short8*)&As[wm * 64 + mi * 16 + lo][rc];
#pragma unroll
            for (int ni = 0; ni < 4; ++ni)
                bfv[ni] = *(const short8*)&Bs[wn * 64 + ni * 16 + lo][rc];
            __builtin_amdgcn_s_setprio(1);
#pragma unroll
            for (int mi = 0; mi < 4; ++mi)
#pragma unroll
                for (int ni = 0; ni < 4; ++ni)
                    acc[mi][ni] = __builtin_amdgcn_mfma_f32_16x16x32_bf16(
                        af[mi], bfv[ni], acc[mi][ni], 0, 0, 0);
            __builtin_amdgcn_s_setprio(0);
        }
        __syncthreads();
    }

#pragma unroll
    for (int mi = 0; mi < 4; ++mi) {
#pragma unroll
        for (int ni = 0; ni < 4; ++ni) {
#pragma unroll
            for (int r = 0; r < 4; ++r) {
                int row = m0 + wm * 64 + mi * 16 + hi * 4 + r;
                int col = n0 + wn * 64 + ni * 16 + lo;
                size_t idx = (size_t)row * N + col;
                float v = acc[mi][ni][r];
                if (EPI == 2) {
                    v += bias[col];
                    v = 0.5f * v * (1.0f + erff(v * 0.70710678118654752f));
                    ((short*)outv)[idx] = f2bf(v);
                } else {
                    v += bias[col] + resid[idx];
                    ((float*)outv)[idx] = v;
                }
            }
        }
    }
}

// ---------------------------------------------------------------------------
// Flash attention + residual + FUSED LayerNorm. Fixed-m softmax (r10).
// 1 barrier/tile; Ps parity double-buffer; grid 256, 8 waves, 64 q-rows.
// ---------------------------------------------------------------------------
__global__ __launch_bounds__(512, 1) void flash_kernel(
    const float* __restrict__ x,    // [8][2048][512] f32
    const short* __restrict__ qbf,  // frag-RC
    const short* __restrict__ kbff, // frag-RC
    const short* __restrict__ vbf,  // frag-CR
    float* __restrict__ xres,       // [8][2048][512] f32
    const float* __restrict__ gamma,
    const float* __restrict__ beta,
    short* __restrict__ hb)         // [16384][512] bf16 (LN output)
{
    __shared__ short Ps[2][2][8][512];   // [buf][qh][key16-blk][lane*8] 32 KB
    __shared__ float lpart[8][32];
    __shared__ float rsum[8][64];
    __shared__ float rsq[8][64];
    __shared__ float murs[2][64];

    const int bid = blockIdx.x;
    const int n = bid & 7;
    const int qtile = bid >> 3;          // 0..31
    const int q0 = qtile << 6;
    const int t = threadIdx.x, l = t & 63, w = t >> 6;
    const int qh = w >> 2, kq = w & 3;
    const int lo5 = l & 31, hi2 = l >> 5;
    const float C1 = 0.08838834764831845f * 1.4426950408889634f; // scale*log2e

    // Q B-fragments for my q-half (32 q-rows)
    short8 qf[8];
    {
        const short* qp = qbf + (((size_t)(n * 64 + qtile * 2 + qh) * 8) << 9) + l * 8;
#pragma unroll
        for (int s = 0; s < 8; ++s) qf[s] = *(const short8*)(qp + (s << 9));
    }

    f32x16 o00 = {}, o01 = {}, o10 = {}, o11 = {};
    float lp = 0.f;

    const short* kb0 = kbff + (((size_t)(n * 64) * 8) << 9);
    const short* vb0 = vbf + ((((size_t)(n * 128)) * 16 + w * 2) << 9);

    short8 preg0, preg1;

    // ---- prologue: QK(0) + exp2 + pack -> Ps[0] ----
    {
        const short* kp = kb0 + (((size_t)kq * 8) << 9) + l * 8;
        short8 kf[8];
#pragma unroll
        for (int s = 0; s < 8; ++s) kf[s] = *(const short8*)(kp + (s << 9));
        f32x16 sa = {};
        __builtin_amdgcn_s_setprio(1);
#pragma unroll
        for (int s = 0; s < 8; ++s)
            sa = __builtin_amdgcn_mfma_f32_32x32x16_bf16(kf[s], qf[s], sa, 0, 0, 0);
        __builtin_amdgcn_s_setprio(0);
        float lsum = 0.f;
#pragma unroll
        for (int r = 0; r < 16; ++r) {
            float p = exp2f(sa[r] * C1);
            sa[r] = p; lsum += p;
        }
        lp = lsum;
        int wq[8], sx[8];
#pragma unroll
        for (int q2 = 0; q2 < 8; ++q2) {
            int a;
            asm("v_cvt_pk_bf16_f32 %0, %1, %2"
                : "=v"(a) : "v"(sa[2 * q2]), "v"(sa[2 * q2 + 1]));
            wq[q2] = a;
        }
#pragma unroll
        for (int q2 = 0; q2 < 8; ++q2) sx[q2] = __shfl_xor(wq[q2], 32);
        union { int i[4]; short8 v; } u0, u1;
        u0.i[0] = hi2 ? sx[2] : wq[0];
        u0.i[1] = hi2 ? sx[3] : wq[1];
        u0.i[2] = hi2 ? wq[2] : sx[0];
        u0.i[3] = hi2 ? wq[3] : sx[1];
        u1.i[0] = hi2 ? sx[6] : wq[4];
        u1.i[1] = hi2 ? sx[7] : wq[5];
        u1.i[2] = hi2 ? wq[6] : sx[4];
        u1.i[3] = hi2 ? wq[7] : sx[5];
        *(short8*)&Ps[0][qh][kq * 2][l * 8]     = u0.v;
        *(short8*)&Ps[0][qh][kq * 2 + 1][l * 8] = u1.v;
    }

    // ---- main loop: 16 tiles of 128 keys, 1 barrier each ----
    for (int kt2 = 0; kt2 < 16; ++kt2) {
        const bool hn = kt2 < 15;
        const short* vp = vb0 + (((size_t)(kt2 * 128)) << 9) + l * 8;

        short8 kf[8];
        if (hn) {
            const short* kp = kb0 + (((size_t)((kt2 + 1) * 4 + kq) * 8) << 9) + l * 8;
#pragma unroll
            for (int s = 0; s < 8; ++s) kf[s] = *(const short8*)(kp + (s << 9));
        }
        short8 vfa[8];
#pragma unroll
        for (int p = 0; p < 8; ++p)
            vfa[p] = *(const short8*)(vp + (((size_t)((p >> 1) * 16 + (p & 1))) << 9));

        if (hn) {
            f32x16 sa = {};
            __builtin_amdgcn_s_setprio(1);
#pragma unroll
            for (int s = 0; s < 8; ++s)
                sa = __builtin_amdgcn_mfma_f32_32x32x16_bf16(kf[s], qf[s], sa, 0, 0, 0);
            __builtin_amdgcn_s_setprio(0);
            float lsum = 0.f;
#pragma unroll
            for (int r = 0; r < 16; ++r) {
                float p = exp2f(sa[r] * C1);
                sa[r] = p; lsum += p;
            }
            lp += lsum;
            int wq[8], sx[8];
#pragma unroll
            for (int q2 = 0; q2 < 8; ++q2) {
                int a;
                asm("v_cvt_pk_bf16_f32 %0, %1, %2"
                    : "=v"(a) : "v"(sa[2 * q2]), "v"(sa[2 * q2 + 1]));
                wq[q2] = a;
            }
#pragma unroll
            for (int q2 = 0; q2 < 8; ++q2) sx[q2] = __shfl_xor(wq[q2], 32);
            union { int i[4]; short8 v; } u0, u1;
            u0.i[0] = hi2 ? sx[2] : wq[0];
            u0.i[1] = hi2 ? sx[3] : wq[1];
            u0.i[2] = hi2 ? wq[2] : sx[0];
            u0.i[3] = hi2 ? wq[3] : sx[1];
            u1.i[0] = hi2 ? sx[6] : wq[4];
            u1.i[1] = hi2 ? sx[7] : wq[5];
            u1.i[2] = hi2 ? wq[6] : sx[4];
            u1.i[3] = hi2 ? wq[7] : sx[5];
            preg0 = u0.v; preg1 = u1.v;
        }

        __syncthreads();   // window boundary: Ps[t&1] ready

        short8 vfb[8];
#pragma unroll
        for (int p = 0; p < 8; ++p)
            vfb[p] = *(const short8*)(vp + (((size_t)((4 + (p >> 1)) * 16 + (p & 1))) << 9));

        if (hn) {
            const int nb2 = (kt2 + 1) & 1;
            *(short8*)&Ps[nb2][qh][kq * 2][l * 8]     = preg0;
            *(short8*)&Ps[nb2][qh][kq * 2 + 1][l * 8] = preg1;
        }

        const int pb = kt2 & 1;
        __builtin_amdgcn_s_setprio(1);
#pragma unroll
        for (int ks = 0; ks < 4; ++ks) {
            short8 p0 = *(const short8*)&Ps[pb][0][ks][l * 8];
            short8 p1 = *(const short8*)&Ps[pb][1][ks][l * 8];
            o00 = __builtin_amdgcn_mfma_f32_32x32x16_bf16(p0, vfa[ks * 2 + 0], o00, 0, 0, 0);
            o01 = __builtin_amdgcn_mfma_f32_32x32x16_bf16(p0, vfa[ks * 2 + 1], o01, 0, 0, 0);
            o10 = __builtin_amdgcn_mfma_f32_32x32x16_bf16(p1, vfa[ks * 2 + 0], o10, 0, 0, 0);
            o11 = __builtin_amdgcn_mfma_f32_32x32x16_bf16(p1, vfa[ks * 2 + 1], o11, 0, 0, 0);
        }
#pragma unroll
        for (int ks = 4; ks < 8; ++ks) {
            short8 p0 = *(const short8*)&Ps[pb][0][ks][l * 8];
            short8 p1 = *(const short8*)&Ps[pb][1][ks][l * 8];
            o00 = __builtin_amdgcn_mfma_f32_32x32x16_bf16(p0, vfb[(ks - 4) * 2 + 0], o00, 0, 0, 0);
            o01 = __builtin_amdgcn_mfma_f32_32x32x16_bf16(p0, vfb[(ks - 4) * 2 + 1], o01, 0, 0, 0);
            o10 = __builtin_amdgcn_mfma_f32_32x32x16_bf16(p1, vfb[(ks - 4) * 2 + 0], o10, 0, 0, 0);
            o11 = __builtin_amdgcn_mfma_f32_32x32x16_bf16(p1, vfb[(ks - 4) * 2 + 1], o11, 0, 0, 0);
        }
        __builtin_amdgcn_s_setprio(0);
    }

    // ---- epilogue: l-merge, normalize, residual -> xres; fused LN -> hb ----
    float l2 = lp + __shfl_xor(lp, 32);
    if (l < 32) lpart[w][l] = l2;
    __syncthreads();
    float li0 = 1.f / (lpart[0][lo5] + lpart[1][lo5] + lpart[2][lo5] + lpart[3][lo5]);
    float li1 = 1.f / (lpart[4][lo5] + lpart[5][lo5] + lpart[6][lo5] + lpart[7][lo5]);
    const int c0 = w * 64 + lo5;
#pragma unroll
    for (int r = 0; r < 16; ++r) {
        int qr = (r & 3) + 8 * (r >> 2) + 4 * hi2;
        float ir0 = __shfl(li0, qr);
        float ir1 = __shfl(li1, qr);
        size_t b0 = ((size_t)(n * 2048 + q0 + qr) << 9) + c0;
        size_t b1 = ((size_t)(n * 2048 + q0 + 32 + qr) << 9) + c0;
        float v00 = x[b0]      + o00[r] * ir0;
        float v01 = x[b0 + 32] + o01[r] * ir0;
        float v10 = x[b1]      + o10[r] * ir1;
        float v11 = x[b1 + 32] + o11[r] * ir1;
        xres[b0] = v00; xres[b0 + 32] = v01;
        xres[b1] = v10; xres[b1 + 32] = v11;
        o00[r] = v00; o01[r] = v01; o10[r] = v10; o11[r] = v11;
        float s0 = v00 + v01, sq0 = v00 * v00 + v01 * v01;
        float s1 = v10 + v11, sq1 = v10 * v10 + v11 * v11;
#pragma unroll
        for (int mm = 1; mm < 32; mm <<= 1) {
            s0 += __shfl_xor(s0, mm); sq0 += __shfl_xor(sq0, mm);
            s1 += __shfl_xor(s1, mm); sq1 += __shfl_xor(sq1, mm);
        }
        if (lo5 == 0) {
            rsum[w][qr] = s0;      rsq[w][qr] = sq0;
            rsum[w][32 + qr] = s1; rsq[w][32 + qr] = sq1;
        }
    }
    __syncthreads();
    if (t < 64) {
        float s = 0.f, qq = 0.f;
#pragma unroll
        for (int ww = 0; ww < 8; ++ww) { s += rsum[ww][t]; qq += rsq[ww][t]; }
        float mu = s * (1.0f / 512.0f);
        float var = qq * (1.0f / 512.0f) - mu * mu;
        murs[0][t] = mu;
        murs[1][t] = rsqrtf(var + 1e-5f);
    }
    __syncthreads();
    const float g0 = gamma[c0], g1 = gamma[c0 + 32];
    const float e0 = beta[c0],  e1 = beta[c0 + 32];
#pragma unroll
    for (int r = 0; r < 16; ++r) {
        int qr = (r & 3) + 8 * (r >> 2) + 4 * hi2;
        float mu0 = murs[0][qr],      rs0 = murs[1][qr];
        float mu1 = murs[0][32 + qr], rs1 = murs[1][32 + qr];
        size_t h0 = ((size_t)(n * 2048 + q0 + qr) << 9) + c0;
        size_t h1 = ((size_t)(n * 2048 + q0 + 32 + qr) << 9) + c0;
        hb[h0]      = f2bf((o00[r] - mu0) * rs0 * g0 + e0);
        hb[h0 + 32] = f2bf((o01[r] - mu0) * rs0 * g1 + e1);
        hb[h1]      = f2bf((o10[r] - mu1) * rs1 * g0 + e0);
        hb[h1 + 32] = f2bf((o11[r] - mu1) * rs1 * g1 + e1);
    }
}

// ---------------------------------------------------------------------------
extern "C" void kernel_launch(void* const* d_in, const int* in_sizes, int n_in,
                              void* d_out, int out_size, void* d_ws, size_t ws_size,
                              hipStream_t stream)
{
    const float* x     = (const float*)d_in[0];
    const float* y     = (const float*)d_in[1];
    const float* Wq    = (const float*)d_in[2];
    const float* Wk    = (const float*)d_in[3];
    const float* Wv    = (const float*)d_in[4];
    const float* gamma = (const float*)d_in[5];
    const float* beta  = (const float*)d_in[6];
    const float* W1    = (const float*)d_in[7];
    const float* b1    = (const float*)d_in[8];
    const float* W2    = (const float*)d_in[9];
    const float* b2    = (const float*)d_in[10];
    float* out = (float*)d_out;

    char* ws = (char*)d_ws;
    size_t off = 0;
    auto alloc = [&](size_t bytes) -> void* {
        void* p = ws + off;
        off += (bytes + 255) & ~(size_t)255;
        return p;
    };
    short* WqT  = (short*)alloc((size_t)128 * 512 * 2);
    short* WkT  = (short*)alloc((size_t)128 * 512 * 2);
    short* WvT  = (short*)alloc((size_t)512 * 512 * 2);
    short* W1T  = (short*)alloc((size_t)1024 * 512 * 2);
    short* W2T  = (short*)alloc((size_t)512 * 1024 * 2);
    short* qbf  = (short*)alloc((size_t)16384 * 128 * 2);   // frag-RC
    short* kbff = (short*)alloc((size_t)16384 * 128 * 2);   // frag-RC
    short* vbf  = (short*)alloc((size_t)16384 * 512 * 2);   // frag-CR
    short* hb   = (short*)alloc((size_t)16384 * 512 * 2);
    short* gb   = (short*)alloc((size_t)16384 * 1024 * 2);

    // 1. prep: weight transposes only
    prep_kernel<<<352, 256, 0, stream>>>(Wq, Wk, Wv, W1, W2,
                                         WqT, WkT, WvT, W1T, W2T);
    // 2. fused q/k/v projections (read f32 x,y directly) -> frag-major
    proj_gemm<<<768, 256, 0, stream>>>(x, y, WqT, WkT, WvT, qbf, kbff, vbf);
    // 3. attention + residual + fused LN -> xres(d_out), hb
    flash_kernel<<<256, 512, 0, stream>>>(x, qbf, kbff, vbf, out, gamma, beta, hb);
    // 4. MLP
    gemm_kernel<2><<<1024, 256, 0, stream>>>(hb, W1T, gb, b1, nullptr, 1024, 512);
    gemm_kernel<3><<<512,  256, 0, stream>>>(gb, W2T, out, b2, out, 512, 1024);

    (void)in_sizes; (void)n_in; (void)out_size; (void)ws_size;
}